// Round 1
// baseline (1039.829 us; speedup 1.0000x reference)
//
#include <hip/hip_runtime.h>
#include <math.h>

#define KC 8     // components
#define DD 16    // dimensions
#define NPT 4    // points per thread (amortizes LDS broadcast reads of A)
#define BLK 256

// ---------------------------------------------------------------------------
// Kernel 1: tiny prep. cov = S S^T, Cholesky L, A = L^{-1} (lower tri),
// b_k = A_k mu_k, c_k = log_softmax(logits)_k - sum(log L_ii) - D/2 log(2pi).
// 1 block, 128 threads: thread (k = tid/16, i = tid%16).
// ---------------------------------------------------------------------------
__global__ __launch_bounds__(128) void gmm_prep(
    const float* __restrict__ logits,
    const float* __restrict__ means,
    const float* __restrict__ scales,
    float* __restrict__ Aout,   // [K][D][D], upper triangle zero-filled
    float* __restrict__ Bout,   // [K][D]
    float* __restrict__ Cout)   // [K]
{
    __shared__ float cov[KC][DD][DD + 1];   // +1 pad: break bank aliasing
    __shared__ float Lsh[KC][DD][DD + 1];
    __shared__ float Ash[KC][DD][DD + 1];

    const int tid = threadIdx.x;
    const int k = tid >> 4;
    const int i = tid & 15;
    const float* Sk = scales + k * DD * DD;

    // cov row i: cov[i][j] = <S_row_i, S_row_j>
    float si[DD];
#pragma unroll
    for (int d = 0; d < DD; ++d) si[d] = Sk[i * DD + d];
    for (int j = 0; j < DD; ++j) {
        float s = 0.f;
#pragma unroll
        for (int d = 0; d < DD; ++d) s += si[d] * Sk[j * DD + d];
        cov[k][i][j] = s;
    }
    __syncthreads();

    // Cooperative left-looking Cholesky (column j per step)
    for (int j = 0; j < DD; ++j) {
        if (i == j) {
            float s = cov[k][j][j];
            for (int t = 0; t < j; ++t) s -= Lsh[k][j][t] * Lsh[k][j][t];
            Lsh[k][j][j] = sqrtf(s);
        }
        __syncthreads();
        if (i > j) {
            float s = cov[k][i][j];
            for (int t = 0; t < j; ++t) s -= Lsh[k][i][t] * Lsh[k][j][t];
            Lsh[k][i][j] = s / Lsh[k][j][j];
        }
        __syncthreads();
    }

    // Invert L: thread (k,i) solves L x = e_i  -> column i of A
    float xc[DD];
#pragma unroll
    for (int r = 0; r < DD; ++r) xc[r] = 0.f;
    for (int r = i; r < DD; ++r) {
        float s = (r == i) ? 1.f : 0.f;
        for (int t = i; t < r; ++t) s -= Lsh[k][r][t] * xc[t];
        xc[r] = s / Lsh[k][r][r];
    }
#pragma unroll
    for (int r = 0; r < DD; ++r) Ash[k][r][i] = xc[r];
    __syncthreads();

    // Write A row i (upper triangle is naturally 0), compute b_i = <A_row_i, mu>
    float bb = 0.f;
    for (int j = 0; j < DD; ++j) {
        float aij = Ash[k][i][j];
        Aout[(k * DD + i) * DD + j] = aij;
        bb += aij * means[k * DD + j];
    }
    Bout[k * DD + i] = bb;

    if (i == 0) {
        float mx = logits[0];
        for (int t = 1; t < KC; ++t) mx = fmaxf(mx, logits[t]);
        float se = 0.f;
        for (int t = 0; t < KC; ++t) se += expf(logits[t] - mx);
        float lse = mx + logf(se);
        float hl = 0.f;
        for (int r = 0; r < DD; ++r) hl += logf(Lsh[k][r][r]);
        const float log2pi = 1.8378770664093453f;
        Cout[k] = (logits[k] - lse) - hl - 0.5f * DD * log2pi;
    }
}

// ---------------------------------------------------------------------------
// Kernel 2: per point n, for each k: y = A_k x - b_k (lower-tri matvec),
// lp_k = c_k - 0.5*||y||^2 ; out = logsumexp_k(lp_k).
// 4 points/thread so LDS broadcast reads of A amortize 4x. All LDS reads are
// wave-uniform addresses (broadcast, conflict-free).
// ---------------------------------------------------------------------------
__global__ __launch_bounds__(BLK) void gmm_lp(
    const float* __restrict__ data,
    const float* __restrict__ Ag,
    const float* __restrict__ Bg,
    const float* __restrict__ Cg,
    float* __restrict__ out, int N)
{
    __shared__ __align__(16) float sA[KC * DD * DD];
    __shared__ float sB[KC * DD];
    __shared__ float sC[KC];
    {
        const float4* a4 = (const float4*)Ag;
        float4* s4 = (float4*)sA;
        for (int t = threadIdx.x; t < KC * DD * DD / 4; t += BLK) s4[t] = a4[t];
        if (threadIdx.x < KC * DD) sB[threadIdx.x] = Bg[threadIdx.x];
        if (threadIdx.x < KC) sC[threadIdx.x] = Cg[threadIdx.x];
    }
    __syncthreads();

    const int base = blockIdx.x * (BLK * NPT) + threadIdx.x;
    float x[NPT][DD];
    int idx[NPT];
#pragma unroll
    for (int p = 0; p < NPT; ++p) {
        int id = base + p * BLK;
        idx[p] = id;
        int cl = id < N ? id : N - 1;  // clamp (guarded store below)
        const float4* xp = (const float4*)(data + (size_t)cl * DD);
#pragma unroll
        for (int q = 0; q < 4; ++q) {
            float4 v = xp[q];
            x[p][4 * q + 0] = v.x; x[p][4 * q + 1] = v.y;
            x[p][4 * q + 2] = v.z; x[p][4 * q + 3] = v.w;
        }
    }

    float lp[NPT][KC];
#pragma unroll
    for (int k = 0; k < KC; ++k) {
        float maha[NPT];
#pragma unroll
        for (int p = 0; p < NPT; ++p) maha[p] = 0.f;
#pragma unroll
        for (int i = 0; i < DD; ++i) {
            float bi = sB[k * DD + i];
            float y[NPT];
#pragma unroll
            for (int p = 0; p < NPT; ++p) y[p] = -bi;
#pragma unroll
            for (int g = 0; g <= i / 4; ++g) {  // A upper triangle is 0 -> full groups OK
                float4 a = *(const float4*)&sA[(k * DD + i) * DD + 4 * g];
#pragma unroll
                for (int p = 0; p < NPT; ++p) {
                    y[p] = fmaf(a.x, x[p][4 * g + 0], y[p]);
                    y[p] = fmaf(a.y, x[p][4 * g + 1], y[p]);
                    y[p] = fmaf(a.z, x[p][4 * g + 2], y[p]);
                    y[p] = fmaf(a.w, x[p][4 * g + 3], y[p]);
                }
            }
#pragma unroll
            for (int p = 0; p < NPT; ++p) maha[p] = fmaf(y[p], y[p], maha[p]);
        }
        float ck = sC[k];
#pragma unroll
        for (int p = 0; p < NPT; ++p) lp[p][k] = fmaf(-0.5f, maha[p], ck);
    }

#pragma unroll
    for (int p = 0; p < NPT; ++p) {
        float mx = lp[p][0];
#pragma unroll
        for (int k = 1; k < KC; ++k) mx = fmaxf(mx, lp[p][k]);
        float s = 0.f;
#pragma unroll
        for (int k = 0; k < KC; ++k) s += __expf(lp[p][k] - mx);
        float r = mx + __logf(s);
        if (idx[p] < N) out[idx[p]] = r;
    }
}

extern "C" void kernel_launch(void* const* d_in, const int* in_sizes, int n_in,
                              void* d_out, int out_size, void* d_ws, size_t ws_size,
                              hipStream_t stream) {
    const float* data   = (const float*)d_in[0];
    const float* logits = (const float*)d_in[1];
    const float* means  = (const float*)d_in[2];
    const float* scales = (const float*)d_in[3];
    float* out = (float*)d_out;
    const int N = in_sizes[0] / DD;

    float* A = (float*)d_ws;            // K*D*D = 2048 floats
    float* B = A + KC * DD * DD;        // K*D   = 128 floats
    float* C = B + KC * DD;             // K     = 8 floats

    gmm_prep<<<1, 128, 0, stream>>>(logits, means, scales, A, B, C);
    const int nblk = (N + BLK * NPT - 1) / (BLK * NPT);
    gmm_lp<<<nblk, BLK, 0, stream>>>(data, A, B, C, out, N);
}

// Round 2
// 120.494 us; speedup vs baseline: 8.6297x; 8.6297x over previous
//
#include <hip/hip_runtime.h>
#include <math.h>

#define KC 8     // components
#define DD 16    // dimensions
#define NPT 2    // points per thread
#define BLK 256

// ---------------------------------------------------------------------------
// Kernel 1: tiny prep. cov = S S^T, Cholesky L, A = L^{-1} (lower tri),
// b_k = A_k mu_k, c_k = log_softmax(logits)_k - sum(log L_ii) - D/2 log(2pi).
// 1 block, 128 threads: thread (k = tid/16, i = tid%16).
// ---------------------------------------------------------------------------
__global__ __launch_bounds__(128) void gmm_prep(
    const float* __restrict__ logits,
    const float* __restrict__ means,
    const float* __restrict__ scales,
    float* __restrict__ Aout,   // [K][D][D], upper triangle zero-filled
    float* __restrict__ Bout,   // [K][D]
    float* __restrict__ Cout)   // [K]
{
    __shared__ float cov[KC][DD][DD + 1];
    __shared__ float Lsh[KC][DD][DD + 1];
    __shared__ float Ash[KC][DD][DD + 1];

    const int tid = threadIdx.x;
    const int k = tid >> 4;
    const int i = tid & 15;
    const float* Sk = scales + k * DD * DD;

    float si[DD];
#pragma unroll
    for (int d = 0; d < DD; ++d) si[d] = Sk[i * DD + d];
    for (int j = 0; j < DD; ++j) {
        float s = 0.f;
#pragma unroll
        for (int d = 0; d < DD; ++d) s += si[d] * Sk[j * DD + d];
        cov[k][i][j] = s;
    }
    __syncthreads();

    for (int j = 0; j < DD; ++j) {
        if (i == j) {
            float s = cov[k][j][j];
            for (int t = 0; t < j; ++t) s -= Lsh[k][j][t] * Lsh[k][j][t];
            Lsh[k][j][j] = sqrtf(s);
        }
        __syncthreads();
        if (i > j) {
            float s = cov[k][i][j];
            for (int t = 0; t < j; ++t) s -= Lsh[k][i][t] * Lsh[k][j][t];
            Lsh[k][i][j] = s / Lsh[k][j][j];
        }
        __syncthreads();
    }

    // Invert L: thread (k,i) solves L x = e_i  -> column i of A
    float xc[DD];
#pragma unroll
    for (int r = 0; r < DD; ++r) xc[r] = 0.f;
    for (int r = i; r < DD; ++r) {
        float s = (r == i) ? 1.f : 0.f;
        for (int t = i; t < r; ++t) s -= Lsh[k][r][t] * xc[t];
        xc[r] = s / Lsh[k][r][r];
    }
#pragma unroll
    for (int r = 0; r < DD; ++r) Ash[k][r][i] = xc[r];
    __syncthreads();

    float bb = 0.f;
    for (int j = 0; j < DD; ++j) {
        float aij = Ash[k][i][j];
        Aout[(k * DD + i) * DD + j] = aij;
        bb += aij * means[k * DD + j];
    }
    Bout[k * DD + i] = bb;

    if (i == 0) {
        float mx = logits[0];
        for (int t = 1; t < KC; ++t) mx = fmaxf(mx, logits[t]);
        float se = 0.f;
        for (int t = 0; t < KC; ++t) se += expf(logits[t] - mx);
        float lse = mx + logf(se);
        float hl = 0.f;
        for (int r = 0; r < DD; ++r) hl += logf(Lsh[k][r][r]);
        const float log2pi = 1.8378770664093453f;
        Cout[k] = (logits[k] - lse) - hl - 0.5f * DD * log2pi;
    }
}

// ---------------------------------------------------------------------------
// Kernel 2: per point: for each k: y = A_k x - b_k (lower-tri matvec),
// lp_k = c_k - 0.5*||y||^2 ; out = online-logsumexp_k(lp_k).
// k-loop kept ROLLED (unroll 1): bounds live registers to one component's
// state (~70 VGPRs) -> no spills (R1 failure mode: 256 VGPR + 1.4 GB spill
// traffic). All LDS reads are wave-uniform broadcasts (conflict-free).
// ---------------------------------------------------------------------------
__global__ __launch_bounds__(BLK, 4) void gmm_lp(
    const float* __restrict__ data,
    const float* __restrict__ Ag,
    const float* __restrict__ Bg,
    const float* __restrict__ Cg,
    float* __restrict__ out, int N)
{
    __shared__ __align__(16) float sA[KC * DD * DD];
    __shared__ __align__(16) float sB[KC * DD];
    __shared__ float sC[KC];
    {
        const float4* a4 = (const float4*)Ag;
        float4* s4 = (float4*)sA;
        for (int t = threadIdx.x; t < KC * DD * DD / 4; t += BLK) s4[t] = a4[t];
        if (threadIdx.x < KC * DD) sB[threadIdx.x] = Bg[threadIdx.x];
        if (threadIdx.x < KC) sC[threadIdx.x] = Cg[threadIdx.x];
    }
    __syncthreads();

    const int base = blockIdx.x * (BLK * NPT) + threadIdx.x;
    float x[NPT][DD];
    int idx[NPT];
#pragma unroll
    for (int p = 0; p < NPT; ++p) {
        int id = base + p * BLK;
        idx[p] = id;
        int cl = id < N ? id : N - 1;  // clamp (guarded store below)
        const float4* xp = (const float4*)(data + (size_t)cl * DD);
#pragma unroll
        for (int q = 0; q < 4; ++q) {
            float4 v = xp[q];
            x[p][4 * q + 0] = v.x; x[p][4 * q + 1] = v.y;
            x[p][4 * q + 2] = v.z; x[p][4 * q + 3] = v.w;
        }
    }

    // online logsumexp state
    float mx[NPT], sum[NPT];
#pragma unroll
    for (int p = 0; p < NPT; ++p) { mx[p] = -1e30f; sum[p] = 0.f; }

#pragma unroll 1
    for (int k = 0; k < KC; ++k) {
        // b_k into registers (4 uniform b128 reads)
        float bk[DD];
        {
            const float4* b4 = (const float4*)&sB[k * DD];
#pragma unroll
            for (int q = 0; q < 4; ++q) {
                float4 v = b4[q];
                bk[4 * q + 0] = v.x; bk[4 * q + 1] = v.y;
                bk[4 * q + 2] = v.z; bk[4 * q + 3] = v.w;
            }
        }
        const float ck = sC[k];
        const float4* Ak = (const float4*)&sA[k * DD * DD];

        float maha[NPT];
#pragma unroll
        for (int p = 0; p < NPT; ++p) maha[p] = 0.f;

#pragma unroll
        for (int i = 0; i < DD; ++i) {
            float y[NPT];
#pragma unroll
            for (int p = 0; p < NPT; ++p) y[p] = -bk[i];
#pragma unroll
            for (int g = 0; g <= i / 4; ++g) {  // upper triangle of A is 0
                float4 a = Ak[i * 4 + g];
#pragma unroll
                for (int p = 0; p < NPT; ++p) {
                    y[p] = fmaf(a.x, x[p][4 * g + 0], y[p]);
                    y[p] = fmaf(a.y, x[p][4 * g + 1], y[p]);
                    y[p] = fmaf(a.z, x[p][4 * g + 2], y[p]);
                    y[p] = fmaf(a.w, x[p][4 * g + 3], y[p]);
                }
            }
#pragma unroll
            for (int p = 0; p < NPT; ++p) maha[p] = fmaf(y[p], y[p], maha[p]);
        }

        // online logsumexp update
#pragma unroll
        for (int p = 0; p < NPT; ++p) {
            float lpk = fmaf(-0.5f, maha[p], ck);
            float nm = fmaxf(mx[p], lpk);
            sum[p] = sum[p] * __expf(mx[p] - nm) + __expf(lpk - nm);
            mx[p] = nm;
        }
    }

#pragma unroll
    for (int p = 0; p < NPT; ++p) {
        float r = mx[p] + __logf(sum[p]);
        if (idx[p] < N) out[idx[p]] = r;
    }
}

extern "C" void kernel_launch(void* const* d_in, const int* in_sizes, int n_in,
                              void* d_out, int out_size, void* d_ws, size_t ws_size,
                              hipStream_t stream) {
    const float* data   = (const float*)d_in[0];
    const float* logits = (const float*)d_in[1];
    const float* means  = (const float*)d_in[2];
    const float* scales = (const float*)d_in[3];
    float* out = (float*)d_out;
    const int N = in_sizes[0] / DD;

    float* A = (float*)d_ws;            // K*D*D = 2048 floats
    float* B = A + KC * DD * DD;        // K*D   = 128 floats
    float* C = B + KC * DD;             // K     = 8 floats

    gmm_prep<<<1, 128, 0, stream>>>(logits, means, scales, A, B, C);
    const int nblk = (N + BLK * NPT - 1) / (BLK * NPT);
    gmm_lp<<<nblk, BLK, 0, stream>>>(data, A, B, C, out, N);
}

// Round 3
// 113.269 us; speedup vs baseline: 9.1802x; 1.0638x over previous
//
#include <hip/hip_runtime.h>
#include <math.h>

#define KC 8     // components
#define DD 16    // dimensions
#define NPT 4    // points per thread
#define BLK 256

// ---------------------------------------------------------------------------
// Kernel 1: tiny prep. cov = S S^T, Cholesky L, A = L^{-1} (lower tri),
// b_k = A_k mu_k, c_k = log_softmax(logits)_k - sum(log L_ii) - D/2 log(2pi).
// 1 block, 128 threads: thread (k = tid/16, i = tid%16).
// R3: no dynamically-indexed private arrays anywhere (R2's xc[t] went to
// scratch -> ~500cyc serial round-trips). Inversion fully unrolled in regs.
// ---------------------------------------------------------------------------
__global__ __launch_bounds__(128) void gmm_prep(
    const float* __restrict__ logits,
    const float* __restrict__ means,
    const float* __restrict__ scales,
    float* __restrict__ Aout,   // [K][D][D], upper triangle zero-filled
    float* __restrict__ Bout,   // [K][D]
    float* __restrict__ Cout)   // [K]
{
    __shared__ float Ssh[KC][DD][DD];       // staged scales
    __shared__ float cov[KC][DD][DD + 1];
    __shared__ float Lsh[KC][DD][DD + 1];
    __shared__ float Ash[KC][DD][DD + 1];

    const int tid = threadIdx.x;
    const int k = tid >> 4;
    const int i = tid & 15;

    // stage S into LDS, coalesced float4
    {
        const float4* s4 = (const float4*)scales;
        float4* d4 = (float4*)&Ssh[0][0][0];
        for (int t = tid; t < KC * DD * DD / 4; t += 128) d4[t] = s4[t];
    }
    __syncthreads();

    // cov row i: cov[i][j] = <S_row_i, S_row_j>
    float si[DD];
#pragma unroll
    for (int d = 0; d < DD; ++d) si[d] = Ssh[k][i][d];
#pragma unroll
    for (int j = 0; j < DD; ++j) {
        float s = 0.f;
#pragma unroll
        for (int d = 0; d < DD; ++d) s = fmaf(si[d], Ssh[k][j][d], s);
        cov[k][i][j] = s;
    }
    __syncthreads();

    // Left-looking Cholesky (column j per step); t-loops are independent
    // LDS loads -> pipelined, no scratch.
    for (int j = 0; j < DD; ++j) {
        if (i == j) {
            float s = cov[k][j][j];
            for (int t = 0; t < j; ++t) s -= Lsh[k][j][t] * Lsh[k][j][t];
            Lsh[k][j][j] = sqrtf(s);
        }
        __syncthreads();
        if (i > j) {
            float s = cov[k][i][j];
            for (int t = 0; t < j; ++t) s -= Lsh[k][i][t] * Lsh[k][j][t];
            Lsh[k][i][j] = s / Lsh[k][j][j];
        }
        __syncthreads();
    }

    // Invert L: thread (k,i) solves L x = e_i -> column i of A.
    // Fully unrolled, compile-time indices only: xc[t]=0 for t<i emerges
    // naturally (s stays 0 until r==i), so no runtime guards needed.
    float xc[DD];
#pragma unroll
    for (int r = 0; r < DD; ++r) {
        float s = (r == i) ? 1.f : 0.f;
#pragma unroll
        for (int t = 0; t < DD; ++t) {
            if (t < r) s -= Lsh[k][r][t] * xc[t];
        }
        xc[r] = (r < i) ? 0.f : (s / Lsh[k][r][r]);
    }
#pragma unroll
    for (int r = 0; r < DD; ++r) Ash[k][r][i] = xc[r];
    __syncthreads();

    // Row i of A: write out + b_i = <A_row_i, mu>
    float bb = 0.f;
#pragma unroll
    for (int j = 0; j < DD; ++j) {
        float aij = Ash[k][i][j];
        Aout[(k * DD + i) * DD + j] = aij;
        bb = fmaf(aij, means[k * DD + j], bb);
    }
    Bout[k * DD + i] = bb;

    if (i == 0) {
        float mx = logits[0];
        for (int t = 1; t < KC; ++t) mx = fmaxf(mx, logits[t]);
        float se = 0.f;
        for (int t = 0; t < KC; ++t) se += expf(logits[t] - mx);
        float lse = mx + logf(se);
        float hl = 0.f;
        for (int r = 0; r < DD; ++r) hl += logf(Lsh[k][r][r]);
        const float log2pi = 1.8378770664093453f;
        Cout[k] = (logits[k] - lse) - hl - 0.5f * DD * log2pi;
    }
}

// ---------------------------------------------------------------------------
// Kernel 2: per point: for each k: y = A_k x - b_k (lower-tri matvec),
// lp_k = c_k - 0.5*||y||^2 ; out = online-logsumexp_k(lp_k).
// R3: NO LDS. A/b/c read from global with wave-uniform addresses ->
// divergence analysis should select s_load (SMEM) + v_fma with SGPR
// operand. R2 was LDS-pipe-bound (360 ds_read_b128/thread, ~66k cyc/CU on
// the per-CU LDS pipe vs ~22k/SIMD VALU). NPT=4 halves per-point overhead;
// k-loop rolled + online LSE keeps regs ~100 (no R1-style spills).
// ---------------------------------------------------------------------------
__global__ __launch_bounds__(BLK, 4) void gmm_lp(
    const float* __restrict__ data,
    const float* __restrict__ Ag,
    const float* __restrict__ Bg,
    const float* __restrict__ Cg,
    float* __restrict__ out, int N)
{
    const int base = blockIdx.x * (BLK * NPT) + threadIdx.x;
    float x[NPT][DD];
    int idx[NPT];
#pragma unroll
    for (int p = 0; p < NPT; ++p) {
        int id = base + p * BLK;
        idx[p] = id;
        int cl = id < N ? id : N - 1;  // clamp (guarded store below)
        const float4* xp = (const float4*)(data + (size_t)cl * DD);
#pragma unroll
        for (int q = 0; q < 4; ++q) {
            float4 v = xp[q];
            x[p][4 * q + 0] = v.x; x[p][4 * q + 1] = v.y;
            x[p][4 * q + 2] = v.z; x[p][4 * q + 3] = v.w;
        }
    }

    float mx[NPT], sum[NPT];
#pragma unroll
    for (int p = 0; p < NPT; ++p) { mx[p] = -1e30f; sum[p] = 0.f; }

#pragma unroll 1
    for (int k = 0; k < KC; ++k) {
        const float* Ak = Ag + k * DD * DD;   // uniform base
        float bk[DD];
        {
            const float4* b4 = (const float4*)(Bg + k * DD);
#pragma unroll
            for (int q = 0; q < 4; ++q) {
                float4 v = b4[q];              // uniform -> s_load_dwordx4
                bk[4 * q + 0] = v.x; bk[4 * q + 1] = v.y;
                bk[4 * q + 2] = v.z; bk[4 * q + 3] = v.w;
            }
        }
        const float ck = Cg[k];

        float maha[NPT];
#pragma unroll
        for (int p = 0; p < NPT; ++p) maha[p] = 0.f;

#pragma unroll
        for (int i = 0; i < DD; ++i) {
            float y[NPT];
#pragma unroll
            for (int p = 0; p < NPT; ++p) y[p] = -bk[i];
#pragma unroll
            for (int g = 0; g <= i / 4; ++g) {  // upper triangle of A is 0
                float4 a = *(const float4*)(Ak + i * DD + 4 * g);  // uniform
#pragma unroll
                for (int p = 0; p < NPT; ++p) {
                    y[p] = fmaf(a.x, x[p][4 * g + 0], y[p]);
                    y[p] = fmaf(a.y, x[p][4 * g + 1], y[p]);
                    y[p] = fmaf(a.z, x[p][4 * g + 2], y[p]);
                    y[p] = fmaf(a.w, x[p][4 * g + 3], y[p]);
                }
            }
#pragma unroll
            for (int p = 0; p < NPT; ++p) maha[p] = fmaf(y[p], y[p], maha[p]);
        }

        // online logsumexp update
#pragma unroll
        for (int p = 0; p < NPT; ++p) {
            float lpk = fmaf(-0.5f, maha[p], ck);
            float nm = fmaxf(mx[p], lpk);
            sum[p] = sum[p] * __expf(mx[p] - nm) + __expf(lpk - nm);
            mx[p] = nm;
        }
    }

#pragma unroll
    for (int p = 0; p < NPT; ++p) {
        float r = mx[p] + __logf(sum[p]);
        if (idx[p] < N) out[idx[p]] = r;
    }
}

extern "C" void kernel_launch(void* const* d_in, const int* in_sizes, int n_in,
                              void* d_out, int out_size, void* d_ws, size_t ws_size,
                              hipStream_t stream) {
    const float* data   = (const float*)d_in[0];
    const float* logits = (const float*)d_in[1];
    const float* means  = (const float*)d_in[2];
    const float* scales = (const float*)d_in[3];
    float* out = (float*)d_out;
    const int N = in_sizes[0] / DD;

    float* A = (float*)d_ws;            // K*D*D = 2048 floats
    float* B = A + KC * DD * DD;        // K*D   = 128 floats
    float* C = B + KC * DD;             // K     = 8 floats

    gmm_prep<<<1, 128, 0, stream>>>(logits, means, scales, A, B, C);
    const int nblk = (N + BLK * NPT - 1) / (BLK * NPT);
    gmm_lp<<<nblk, BLK, 0, stream>>>(data, A, B, C, out, N);
}

// Round 4
// 110.553 us; speedup vs baseline: 9.4057x; 1.0246x over previous
//
#include <hip/hip_runtime.h>
#include <math.h>

#define KC 8     // components
#define DD 16    // dimensions
#define NPT 1    // points per thread: maximize grid size / occupancy
#define BLK 256

// ---------------------------------------------------------------------------
// Kernel 1: tiny prep. cov = S S^T, Cholesky L, A = L^{-1} (lower tri),
// b_k = A_k mu_k, c_k = log_softmax(logits)_k - sum(log L_ii) - D/2 log(2pi).
// 1 block, 128 threads: thread (k = tid/16, i = tid%16).
// ---------------------------------------------------------------------------
__global__ __launch_bounds__(128) void gmm_prep(
    const float* __restrict__ logits,
    const float* __restrict__ means,
    const float* __restrict__ scales,
    float* __restrict__ Aout,   // [K][D][D], upper triangle zero-filled
    float* __restrict__ Bout,   // [K][D]
    float* __restrict__ Cout)   // [K]
{
    __shared__ float Ssh[KC][DD][DD];
    __shared__ float cov[KC][DD][DD + 1];
    __shared__ float Lsh[KC][DD][DD + 1];
    __shared__ float Ash[KC][DD][DD + 1];

    const int tid = threadIdx.x;
    const int k = tid >> 4;
    const int i = tid & 15;

    {
        const float4* s4 = (const float4*)scales;
        float4* d4 = (float4*)&Ssh[0][0][0];
        for (int t = tid; t < KC * DD * DD / 4; t += 128) d4[t] = s4[t];
    }
    __syncthreads();

    float si[DD];
#pragma unroll
    for (int d = 0; d < DD; ++d) si[d] = Ssh[k][i][d];
#pragma unroll
    for (int j = 0; j < DD; ++j) {
        float s = 0.f;
#pragma unroll
        for (int d = 0; d < DD; ++d) s = fmaf(si[d], Ssh[k][j][d], s);
        cov[k][i][j] = s;
    }
    __syncthreads();

    for (int j = 0; j < DD; ++j) {
        if (i == j) {
            float s = cov[k][j][j];
            for (int t = 0; t < j; ++t) s -= Lsh[k][j][t] * Lsh[k][j][t];
            Lsh[k][j][j] = sqrtf(s);
        }
        __syncthreads();
        if (i > j) {
            float s = cov[k][i][j];
            for (int t = 0; t < j; ++t) s -= Lsh[k][i][t] * Lsh[k][j][t];
            Lsh[k][i][j] = s / Lsh[k][j][j];
        }
        __syncthreads();
    }

    // Invert L (fully unrolled, compile-time indices only -> stays in regs)
    float xc[DD];
#pragma unroll
    for (int r = 0; r < DD; ++r) {
        float s = (r == i) ? 1.f : 0.f;
#pragma unroll
        for (int t = 0; t < DD; ++t) {
            if (t < r) s -= Lsh[k][r][t] * xc[t];
        }
        xc[r] = (r < i) ? 0.f : (s / Lsh[k][r][r]);
    }
#pragma unroll
    for (int r = 0; r < DD; ++r) Ash[k][r][i] = xc[r];
    __syncthreads();

    float bb = 0.f;
#pragma unroll
    for (int j = 0; j < DD; ++j) {
        float aij = Ash[k][i][j];
        Aout[(k * DD + i) * DD + j] = aij;
        bb = fmaf(aij, means[k * DD + j], bb);
    }
    Bout[k * DD + i] = bb;

    if (i == 0) {
        float mx = logits[0];
        for (int t = 1; t < KC; ++t) mx = fmaxf(mx, logits[t]);
        float se = 0.f;
        for (int t = 0; t < KC; ++t) se += expf(logits[t] - mx);
        float lse = mx + logf(se);
        float hl = 0.f;
        for (int r = 0; r < DD; ++r) hl += logf(Lsh[k][r][r]);
        const float log2pi = 1.8378770664093453f;
        Cout[k] = (logits[k] - lse) - hl - 0.5f * DD * log2pi;
    }
}

// ---------------------------------------------------------------------------
// Kernel 2: per point: for each k: y = A_k x - b_k (lower-tri matvec),
// lp_k = c_k - 0.5*||y||^2 ; out = online-logsumexp_k(lp_k).
// R4: NPT=1 -> grid 1954 blocks = 7.6 blocks/CU; __launch_bounds__(256,6)
// (84-VGPR cap, ~55 needed) -> ~6 waves/SIMD to hide the rolled k-loop's
// operand-load latency + exp chain (R3 ran at 1.9 waves/SIMD, ~25% VALU).
// A/b/c reads are wave-uniform from global (scalarizable to s_load); no LDS.
// ---------------------------------------------------------------------------
__global__ __launch_bounds__(BLK, 6) void gmm_lp(
    const float* __restrict__ data,
    const float* __restrict__ Ag,
    const float* __restrict__ Bg,
    const float* __restrict__ Cg,
    float* __restrict__ out, int N)
{
    const int id = blockIdx.x * BLK + threadIdx.x;
    const int cl = id < N ? id : N - 1;   // clamp (guarded store below)

    float x[DD];
    {
        const float4* xp = (const float4*)(data + (size_t)cl * DD);
#pragma unroll
        for (int q = 0; q < 4; ++q) {
            float4 v = xp[q];
            x[4 * q + 0] = v.x; x[4 * q + 1] = v.y;
            x[4 * q + 2] = v.z; x[4 * q + 3] = v.w;
        }
    }

    float mx = -1e30f, sum = 0.f;

#pragma unroll 1
    for (int k = 0; k < KC; ++k) {
        const float* Ak = Ag + k * DD * DD;   // uniform base
        float bk[DD];
        {
            const float4* b4 = (const float4*)(Bg + k * DD);
#pragma unroll
            for (int q = 0; q < 4; ++q) {
                float4 v = b4[q];              // uniform -> s_load
                bk[4 * q + 0] = v.x; bk[4 * q + 1] = v.y;
                bk[4 * q + 2] = v.z; bk[4 * q + 3] = v.w;
            }
        }
        const float ck = Cg[k];

        float maha = 0.f;
#pragma unroll
        for (int i = 0; i < DD; ++i) {
            float y = -bk[i];
#pragma unroll
            for (int g = 0; g <= i / 4; ++g) {  // upper triangle of A is 0
                float4 a = *(const float4*)(Ak + i * DD + 4 * g);  // uniform
                y = fmaf(a.x, x[4 * g + 0], y);
                y = fmaf(a.y, x[4 * g + 1], y);
                y = fmaf(a.z, x[4 * g + 2], y);
                y = fmaf(a.w, x[4 * g + 3], y);
            }
            maha = fmaf(y, y, maha);
        }

        float lpk = fmaf(-0.5f, maha, ck);
        float nm = fmaxf(mx, lpk);
        sum = sum * __expf(mx - nm) + __expf(lpk - nm);
        mx = nm;
    }

    if (id < N) out[id] = mx + __logf(sum);
}

extern "C" void kernel_launch(void* const* d_in, const int* in_sizes, int n_in,
                              void* d_out, int out_size, void* d_ws, size_t ws_size,
                              hipStream_t stream) {
    const float* data   = (const float*)d_in[0];
    const float* logits = (const float*)d_in[1];
    const float* means  = (const float*)d_in[2];
    const float* scales = (const float*)d_in[3];
    float* out = (float*)d_out;
    const int N = in_sizes[0] / DD;

    float* A = (float*)d_ws;            // K*D*D = 2048 floats
    float* B = A + KC * DD * DD;        // K*D   = 128 floats
    float* C = B + KC * DD;             // K     = 8 floats

    gmm_prep<<<1, 128, 0, stream>>>(logits, means, scales, A, B, C);
    const int nblk = (N + BLK * NPT - 1) / (BLK * NPT);
    gmm_lp<<<nblk, BLK, 0, stream>>>(data, A, B, C, out, N);
}

// Round 5
// 105.542 us; speedup vs baseline: 9.8523x; 1.0475x over previous
//
#include <hip/hip_runtime.h>
#include <math.h>

#define KC 8     // components
#define DD 16    // dimensions
#define BLK 256

// ---------------------------------------------------------------------------
// Kernel 1: prep, register+shuffle edition (R4 post-mortem: old version was
// 53 us at VALUBusy 0.01% -- rolled t-loops emitted per-iteration ds_read +
// lgkmcnt(0) waits, ~250 cyc each, x240, plus 33 barriers on 2 waves).
// Here: rows live in registers; cross-lane row access via __shfl with
// compile-time register indices; fully unrolled; ONE barrier (transpose).
// Thread (k = tid/16, i = tid%16), 128 threads. Within a wave, matrix k's
// row j lives at lane (lane & 48) | j.
// ---------------------------------------------------------------------------
__global__ __launch_bounds__(128) void gmm_prep(
    const float* __restrict__ logits,
    const float* __restrict__ means,
    const float* __restrict__ scales,
    float* __restrict__ Aout,   // [K][D][D] row-major, upper triangle zeroed
    float* __restrict__ Bout,   // [K][D]
    float* __restrict__ Cout)   // [K]
{
    const int tid  = threadIdx.x;
    const int k    = tid >> 4;
    const int i    = tid & 15;
    const int lane = tid & 63;
    const int base = lane & 48;     // lane of row 0 of this matrix, in-wave

    // ---- load S row i of component k into registers (coalesced float4) ----
    float srow[DD];
    {
        const float4* sp = (const float4*)(scales + (size_t)(k * DD + i) * DD);
#pragma unroll
        for (int q = 0; q < 4; ++q) {
            float4 v = sp[q];
            srow[4 * q + 0] = v.x; srow[4 * q + 1] = v.y;
            srow[4 * q + 2] = v.z; srow[4 * q + 3] = v.w;
        }
    }

    // ---- cov row i: a[j] = <S_i, S_j>, S_j[d] via shfl (reg idx d is
    //      compile-time; 256 shfl + 256 fma, no memory) ----
    float a[DD];
#pragma unroll
    for (int j = 0; j < DD; ++j) a[j] = 0.f;
#pragma unroll
    for (int d = 0; d < DD; ++d) {
        float sid = srow[d];
#pragma unroll
        for (int j = 0; j < DD; ++j) {
            float sjd = __shfl(srow[d], base + j, 64);
            a[j] = fmaf(sid, sjd, a[j]);
        }
    }

    // ---- right-looking Cholesky on register rows, fully unrolled ----
    float l[DD];
    float hld = 0.f;                 // sum_j log L[j][j], same on all lanes
#pragma unroll
    for (int j = 0; j < DD; ++j) {
        float ajj = __shfl(a[j], base + j, 64);   // diag after prior updates
        float ljj = sqrtf(ajj);
        hld += logf(ljj);
        float lij = (i < j) ? 0.f : (a[j] / ljj); // i==j gives ljj exactly
        l[j] = lij;
#pragma unroll
        for (int c = j + 1; c < DD; ++c) {
            float lcj = __shfl(l[j], base + c, 64);
            a[c] = fmaf(-lij, lcj, a[c]);         // trailing rank-1 update
        }
    }

    // ---- invert L: thread (k,i) computes column i of A = L^{-1} ----
    // xc[r] = (delta_ri - sum_{t<r} L[r][t] xc[t]) / L[r][r]; zeros for r<i
    // emerge naturally (xc[t<i]=0). All L accesses via shfl, compile-time.
    float xc[DD];
#pragma unroll
    for (int r = 0; r < DD; ++r) {
        float s = (r == i) ? 1.f : 0.f;
#pragma unroll
        for (int t = 0; t < DD; ++t) {
            if (t < r) {
                float lrt = __shfl(l[t], base + r, 64);
                s = fmaf(-lrt, xc[t], s);
            }
        }
        float lrr = __shfl(l[r], base + r, 64);
        xc[r] = (r < i) ? 0.f : (s / lrr);
    }

    // ---- transpose columns->rows via LDS (only LDS use; +1 pad) ----
    __shared__ float Ash[KC][DD][DD + 1];
#pragma unroll
    for (int r = 0; r < DD; ++r) Ash[k][r][i] = xc[r];
    __syncthreads();

    // ---- write A row i, b_i = <A_i, mu> ----
    float bb = 0.f;
#pragma unroll
    for (int j = 0; j < DD; ++j) {
        float aij = Ash[k][i][j];
        Aout[(k * DD + i) * DD + j] = aij;
        bb = fmaf(aij, means[k * DD + j], bb);
    }
    Bout[k * DD + i] = bb;

    if (i == 0) {
        float mx = logits[0];
        for (int t = 1; t < KC; ++t) mx = fmaxf(mx, logits[t]);
        float se = 0.f;
        for (int t = 0; t < KC; ++t) se += expf(logits[t] - mx);
        float lse = mx + logf(se);
        const float log2pi = 1.8378770664093453f;
        Cout[k] = (logits[k] - lse) - hld - 0.5f * DD * log2pi;
    }
}

// ---------------------------------------------------------------------------
// Kernel 2 (unchanged from R4, ~VALU floor): per point, for each k:
// y = A_k x - b_k (lower-tri matvec), lp_k = c_k - 0.5*||y||^2;
// out = online-logsumexp_k. NPT=1 -> 1954 blocks, ~6 waves/SIMD.
// A/b/c reads are wave-uniform from global (scalar s_load path); no LDS.
// ---------------------------------------------------------------------------
__global__ __launch_bounds__(BLK, 6) void gmm_lp(
    const float* __restrict__ data,
    const float* __restrict__ Ag,
    const float* __restrict__ Bg,
    const float* __restrict__ Cg,
    float* __restrict__ out, int N)
{
    const int id = blockIdx.x * BLK + threadIdx.x;
    const int cl = id < N ? id : N - 1;   // clamp (guarded store below)

    float x[DD];
    {
        const float4* xp = (const float4*)(data + (size_t)cl * DD);
#pragma unroll
        for (int q = 0; q < 4; ++q) {
            float4 v = xp[q];
            x[4 * q + 0] = v.x; x[4 * q + 1] = v.y;
            x[4 * q + 2] = v.z; x[4 * q + 3] = v.w;
        }
    }

    float mx = -1e30f, sum = 0.f;

#pragma unroll 1
    for (int k = 0; k < KC; ++k) {
        const float* Ak = Ag + k * DD * DD;   // uniform base
        float bk[DD];
        {
            const float4* b4 = (const float4*)(Bg + k * DD);
#pragma unroll
            for (int q = 0; q < 4; ++q) {
                float4 v = b4[q];              // uniform -> s_load
                bk[4 * q + 0] = v.x; bk[4 * q + 1] = v.y;
                bk[4 * q + 2] = v.z; bk[4 * q + 3] = v.w;
            }
        }
        const float ck = Cg[k];

        float maha = 0.f;
#pragma unroll
        for (int i = 0; i < DD; ++i) {
            float y = -bk[i];
#pragma unroll
            for (int g = 0; g <= i / 4; ++g) {  // upper triangle of A is 0
                float4 a = *(const float4*)(Ak + i * DD + 4 * g);  // uniform
                y = fmaf(a.x, x[4 * g + 0], y);
                y = fmaf(a.y, x[4 * g + 1], y);
                y = fmaf(a.z, x[4 * g + 2], y);
                y = fmaf(a.w, x[4 * g + 3], y);
            }
            maha = fmaf(y, y, maha);
        }

        float lpk = fmaf(-0.5f, maha, ck);
        float nm = fmaxf(mx, lpk);
        sum = sum * __expf(mx - nm) + __expf(lpk - nm);
        mx = nm;
    }

    if (id < N) out[id] = mx + __logf(sum);
}

extern "C" void kernel_launch(void* const* d_in, const int* in_sizes, int n_in,
                              void* d_out, int out_size, void* d_ws, size_t ws_size,
                              hipStream_t stream) {
    const float* data   = (const float*)d_in[0];
    const float* logits = (const float*)d_in[1];
    const float* means  = (const float*)d_in[2];
    const float* scales = (const float*)d_in[3];
    float* out = (float*)d_out;
    const int N = in_sizes[0] / DD;

    float* A = (float*)d_ws;            // K*D*D = 2048 floats
    float* B = A + KC * DD * DD;        // K*D   = 128 floats
    float* C = B + KC * DD;             // K     = 8 floats

    gmm_prep<<<1, 128, 0, stream>>>(logits, means, scales, A, B, C);
    const int nblk = (N + BLK - 1) / BLK;
    gmm_lp<<<nblk, BLK, 0, stream>>>(data, A, B, C, out, N);
}

// Round 6
// 96.515 us; speedup vs baseline: 10.7738x; 1.0935x over previous
//
#include <hip/hip_runtime.h>
#include <math.h>

#define KC 8
#define DD 16
#define BLK 256

typedef short short8 __attribute__((ext_vector_type(8)));   // 8 bf16 (4 VGPRs)
typedef float floatx4 __attribute__((ext_vector_type(4)));  // MFMA acc

// round-to-nearest-even bf16, returned as bits in HIGH 16 (low 16 zero)
__device__ __forceinline__ unsigned bf16h(float x) {
    unsigned u = __float_as_uint(x);
    return (u + 0x7FFFu + ((u >> 16) & 1u)) & 0xFFFF0000u;
}

// ---------------------------------------------------------------------------
// Kernel 1: prep (R5 shuffle Cholesky/inverse, ~3 us) + NEW: emit A' in MFMA
// A-fragment layout, split bf16 hi/lo. A' is 16x32: cols 0..15 = L^{-1}
// (lower tri), col 16 = -b_k (so MFMA computes A x - b against X row16 = 1),
// cols 17..31 = 0. Fragment: lane l of comp k holds A'[m=l&15][(l>>4)*8+j],
// j=0..7, as 4 dwords of packed bf16x2 (even k low, odd k high).
// ---------------------------------------------------------------------------
__global__ __launch_bounds__(128) void gmm_prep(
    const float* __restrict__ logits,
    const float* __restrict__ means,
    const float* __restrict__ scales,
    uint4* __restrict__ AH,     // [KC][64] fragment dwords, hi
    uint4* __restrict__ AL,     // [KC][64] fragment dwords, lo
    float* __restrict__ Cout)   // [KC]
{
    const int tid  = threadIdx.x;
    const int k    = tid >> 4;
    const int i    = tid & 15;
    const int lane = tid & 63;
    const int base = lane & 48;

    // S row i of comp k -> registers
    float srow[DD];
    {
        const float4* sp = (const float4*)(scales + (size_t)(k * DD + i) * DD);
#pragma unroll
        for (int q = 0; q < 4; ++q) {
            float4 v = sp[q];
            srow[4 * q + 0] = v.x; srow[4 * q + 1] = v.y;
            srow[4 * q + 2] = v.z; srow[4 * q + 3] = v.w;
        }
    }

    // cov row i via shfl
    float a[DD];
#pragma unroll
    for (int j = 0; j < DD; ++j) a[j] = 0.f;
#pragma unroll
    for (int d = 0; d < DD; ++d) {
        float sid = srow[d];
#pragma unroll
        for (int j = 0; j < DD; ++j) {
            float sjd = __shfl(srow[d], base + j, 64);
            a[j] = fmaf(sid, sjd, a[j]);
        }
    }

    // right-looking Cholesky in registers
    float l[DD];
    float hld = 0.f;
#pragma unroll
    for (int j = 0; j < DD; ++j) {
        float ajj = __shfl(a[j], base + j, 64);
        float ljj = sqrtf(ajj);
        hld += logf(ljj);
        float lij = (i < j) ? 0.f : (a[j] / ljj);
        l[j] = lij;
#pragma unroll
        for (int c = j + 1; c < DD; ++c) {
            float lcj = __shfl(l[j], base + c, 64);
            a[c] = fmaf(-lij, lcj, a[c]);
        }
    }

    // invert L: thread (k,i) -> column i of A
    float xc[DD];
#pragma unroll
    for (int r = 0; r < DD; ++r) {
        float s = (r == i) ? 1.f : 0.f;
#pragma unroll
        for (int t = 0; t < DD; ++t) {
            if (t < r) {
                float lrt = __shfl(l[t], base + r, 64);
                s = fmaf(-lrt, xc[t], s);
            }
        }
        float lrr = __shfl(l[r], base + r, 64);
        xc[r] = (r < i) ? 0.f : (s / lrr);
    }

    // transpose columns->rows via LDS
    __shared__ float Ash[KC][DD][DD + 1];
#pragma unroll
    for (int r = 0; r < DD; ++r) Ash[k][r][i] = xc[r];
    __syncthreads();

    // row i of A + b_i
    float rowv[32];
    float bb = 0.f;
#pragma unroll
    for (int j = 0; j < DD; ++j) {
        float aij = Ash[k][i][j];
        rowv[j] = aij;
        bb = fmaf(aij, means[k * DD + j], bb);
    }
    rowv[16] = -bb;
#pragma unroll
    for (int j = 17; j < 32; ++j) rowv[j] = 0.f;

    // emit fragments: quads q=0..3 (lane q*16+i), dwords jj=0..3
#pragma unroll
    for (int q = 0; q < 4; ++q) {
        unsigned dh[4], dl[4];
#pragma unroll
        for (int jj = 0; jj < 4; ++jj) {
            float e = rowv[q * 8 + 2 * jj];
            float o = rowv[q * 8 + 2 * jj + 1];
            unsigned he = bf16h(e), ho = bf16h(o);
            float re = e - __uint_as_float(he);
            float ro = o - __uint_as_float(ho);
            dh[jj] = ho | (he >> 16);
            dl[jj] = bf16h(ro) | (bf16h(re) >> 16);
        }
        AH[k * 64 + q * 16 + i] = make_uint4(dh[0], dh[1], dh[2], dh[3]);
        AL[k * 64 + q * 16 + i] = make_uint4(dl[0], dl[1], dl[2], dl[3]);
    }

    if (i == 0) {
        float mx = logits[0];
        for (int t = 1; t < KC; ++t) mx = fmaxf(mx, logits[t]);
        float se = 0.f;
        for (int t = 0; t < KC; ++t) se += expf(logits[t] - mx);
        float lse = mx + logf(se);
        const float log2pi = 1.8378770664093453f;
        Cout[k] = (logits[k] - lse) - hld - 0.5f * DD * log2pi;
    }
}

// ---------------------------------------------------------------------------
// Kernel 2: MFMA edition. Wave handles 64 consecutive points. Each lane loads
// its point, splits to bf16 hi/lo, transposes to B-fragment layout through
// per-wave-private LDS (no barriers). Then per comp k: 4 point-tiles x 3
// split-precision MFMAs (16x16x32 bf16); maha = cross-quad shfl-xor reduce of
// sum(acc^2); online logsumexp per lane for its own point.
// ---------------------------------------------------------------------------
__global__ __launch_bounds__(BLK, 4) void gmm_lp(
    const float* __restrict__ data,
    const uint4* __restrict__ AH,
    const uint4* __restrict__ AL,
    const float* __restrict__ Cg,
    float* __restrict__ out, int N)
{
    __shared__ unsigned lds[4 * 1536];   // per wave: hi [64 pts][12 dw], lo +768

    const int tid  = threadIdx.x;
    const int lane = tid & 63;
    const int wv   = tid >> 6;
    const int id   = blockIdx.x * BLK + tid;
    const int cl   = id < N ? id : N - 1;

    // load my point
    float x[DD];
    {
        const float4* xp = (const float4*)(data + (size_t)cl * DD);
#pragma unroll
        for (int q = 0; q < 4; ++q) {
            float4 v = xp[q];
            x[4 * q + 0] = v.x; x[4 * q + 1] = v.y;
            x[4 * q + 2] = v.z; x[4 * q + 3] = v.w;
        }
    }

    // split to bf16 hi/lo, pack pairs (even low, odd high)
    unsigned dh[8], dl[8];
#pragma unroll
    for (int jj = 0; jj < 8; ++jj) {
        float e = x[2 * jj], o = x[2 * jj + 1];
        unsigned he = bf16h(e), ho = bf16h(o);
        float re = e - __uint_as_float(he);
        float ro = o - __uint_as_float(ho);
        dh[jj] = ho | (he >> 16);
        dl[jj] = bf16h(ro) | (bf16h(re) >> 16);
    }

    // stage to LDS (wave-private region; stride 12 dwords kills conflicts)
    const int wb = wv * 1536 + lane * 12;
    *(uint4*)&lds[wb + 0] = make_uint4(dh[0], dh[1], dh[2], dh[3]);
    *(uint4*)&lds[wb + 4] = make_uint4(dh[4], dh[5], dh[6], dh[7]);
    *(uint4*)&lds[wb + 768 + 0] = make_uint4(dl[0], dl[1], dl[2], dl[3]);
    *(uint4*)&lds[wb + 768 + 4] = make_uint4(dl[4], dl[5], dl[6], dl[7]);
    // no barrier: intra-wave producer/consumer only (lgkmcnt suffices)

    // gather B-fragments for 4 point-tiles
    const int q = lane >> 4, c = lane & 15;
    short8 bh[4], bl[4];
#pragma unroll
    for (int t = 0; t < 4; ++t) {
        uint4 uh, ul;
        if (q < 2) {
            int ad = wv * 1536 + (16 * t + c) * 12 + q * 4;
            uh = *(const uint4*)&lds[ad];
            ul = *(const uint4*)&lds[ad + 768];
        } else if (q == 2) {
            uh = make_uint4(0x00003F80u, 0u, 0u, 0u);  // k=16 row: X=1.0
            ul = make_uint4(0u, 0u, 0u, 0u);
        } else {
            uh = make_uint4(0u, 0u, 0u, 0u);
            ul = make_uint4(0u, 0u, 0u, 0u);
        }
        bh[t] = __builtin_bit_cast(short8, uh);
        bl[t] = __builtin_bit_cast(short8, ul);
    }

    float mx = -1e30f, sum = 0.f;

#pragma unroll 1
    for (int k = 0; k < KC; ++k) {
        short8 ah = __builtin_bit_cast(short8, AH[k * 64 + lane]);
        short8 al = __builtin_bit_cast(short8, AL[k * 64 + lane]);
        float ck = Cg[k];

        floatx4 acc[4];
#pragma unroll
        for (int t = 0; t < 4; ++t) {
            floatx4 z = {0.f, 0.f, 0.f, 0.f};
            floatx4 a0 = __builtin_amdgcn_mfma_f32_16x16x32_bf16(ah, bh[t], z, 0, 0, 0);
            a0 = __builtin_amdgcn_mfma_f32_16x16x32_bf16(ah, bl[t], a0, 0, 0, 0);
            a0 = __builtin_amdgcn_mfma_f32_16x16x32_bf16(al, bh[t], a0, 0, 0, 0);
            acc[t] = a0;
        }

        // maha per tile: sum 4 regs' squares, then reduce across quads
        float s[4];
#pragma unroll
        for (int t = 0; t < 4; ++t) {
            float v = acc[t][0] * acc[t][0];
            v = fmaf(acc[t][1], acc[t][1], v);
            v = fmaf(acc[t][2], acc[t][2], v);
            v = fmaf(acc[t][3], acc[t][3], v);
            v += __shfl_xor(v, 16, 64);
            v += __shfl_xor(v, 32, 64);
            s[t] = v;
        }
        // lane owns point tile t == q
        float m01 = (q & 1) ? s[1] : s[0];
        float m23 = (q & 1) ? s[3] : s[2];
        float mm  = (q & 2) ? m23 : m01;

        float lpk = fmaf(-0.5f, mm, ck);
        float nm = fmaxf(mx, lpk);
        sum = sum * __expf(mx - nm) + __expf(lpk - nm);
        mx = nm;
    }

    if (id < N) out[id] = mx + __logf(sum);
}

extern "C" void kernel_launch(void* const* d_in, const int* in_sizes, int n_in,
                              void* d_out, int out_size, void* d_ws, size_t ws_size,
                              hipStream_t stream) {
    const float* data   = (const float*)d_in[0];
    const float* logits = (const float*)d_in[1];
    const float* means  = (const float*)d_in[2];
    const float* scales = (const float*)d_in[3];
    float* out = (float*)d_out;
    const int N = in_sizes[0] / DD;

    uint4* AH = (uint4*)d_ws;            // 512 uint4 = 8 KB
    uint4* AL = AH + KC * 64;            // 8 KB
    float* C  = (float*)(AL + KC * 64);  // 8 floats

    gmm_prep<<<1, 128, 0, stream>>>(logits, means, scales, AH, AL, C);
    const int nblk = (N + BLK - 1) / BLK;
    gmm_lp<<<nblk, BLK, 0, stream>>>(data, AH, AL, C, out, N);
}

// Round 7
// 92.328 us; speedup vs baseline: 11.2623x; 1.0453x over previous
//
#include <hip/hip_runtime.h>
#include <math.h>

#define KC 8
#define DD 16
#define BLK 256

typedef short short8 __attribute__((ext_vector_type(8)));    // 8 bf16 (4 VGPRs)
typedef float floatx16 __attribute__((ext_vector_type(16))); // 32x32 MFMA acc

__device__ __forceinline__ unsigned asu(float x) { return __float_as_uint(x); }

// ---------------------------------------------------------------------------
// Kernel 1: prep (R5 shuffle Cholesky/inverse) emitting for the 32x32x16
// MFMA pipeline:
//  - AH2/AL2: A-fragments of Ap = [L^-1_{2P} ; L^-1_{2P+1}] (32x16), split
//    bf16 hi/lo (truncate + residual). Lane l holds Ap[m=l&31][k=(l>>5)*8+j].
//  - BF: -b in 32x32 C-layout (row=(t&3)+8*(t>>2)+4*h), per pair P, half h:
//    acc-init vector so MFMA computes A(x)-b directly.
//  - Cout: mix log-weight - sum log L_ii - D/2 log2pi.
// ---------------------------------------------------------------------------
__global__ __launch_bounds__(128) void gmm_prep(
    const float* __restrict__ logits,
    const float* __restrict__ means,
    const float* __restrict__ scales,
    uint4* __restrict__ AH2,    // [4 pairs][64 lanes]
    uint4* __restrict__ AL2,    // [4 pairs][64 lanes]
    float* __restrict__ BF,     // [4 pairs][2 halves][16] = -b acc-init
    float* __restrict__ Cout)   // [KC]
{
    const int tid  = threadIdx.x;
    const int k    = tid >> 4;
    const int i    = tid & 15;
    const int lane = tid & 63;
    const int base = lane & 48;

    // S row i of comp k -> registers
    float srow[DD];
    {
        const float4* sp = (const float4*)(scales + (size_t)(k * DD + i) * DD);
#pragma unroll
        for (int q = 0; q < 4; ++q) {
            float4 v = sp[q];
            srow[4 * q + 0] = v.x; srow[4 * q + 1] = v.y;
            srow[4 * q + 2] = v.z; srow[4 * q + 3] = v.w;
        }
    }

    // cov row i via shfl
    float a[DD];
#pragma unroll
    for (int j = 0; j < DD; ++j) a[j] = 0.f;
#pragma unroll
    for (int d = 0; d < DD; ++d) {
        float sid = srow[d];
#pragma unroll
        for (int j = 0; j < DD; ++j) {
            float sjd = __shfl(srow[d], base + j, 64);
            a[j] = fmaf(sid, sjd, a[j]);
        }
    }

    // right-looking Cholesky in registers
    float l[DD];
    float hld = 0.f;
#pragma unroll
    for (int j = 0; j < DD; ++j) {
        float ajj = __shfl(a[j], base + j, 64);
        float ljj = sqrtf(ajj);
        hld += logf(ljj);
        float lij = (i < j) ? 0.f : (a[j] / ljj);
        l[j] = lij;
#pragma unroll
        for (int c = j + 1; c < DD; ++c) {
            float lcj = __shfl(l[j], base + c, 64);
            a[c] = fmaf(-lij, lcj, a[c]);
        }
    }

    // invert L: thread (k,i) -> column i of A = L^{-1}
    float xc[DD];
#pragma unroll
    for (int r = 0; r < DD; ++r) {
        float s = (r == i) ? 1.f : 0.f;
#pragma unroll
        for (int t = 0; t < DD; ++t) {
            if (t < r) {
                float lrt = __shfl(l[t], base + r, 64);
                s = fmaf(-lrt, xc[t], s);
            }
        }
        float lrr = __shfl(l[r], base + r, 64);
        xc[r] = (r < i) ? 0.f : (s / lrr);
    }

    // transpose columns->rows via LDS
    __shared__ float Ash[KC][DD][DD + 1];
#pragma unroll
    for (int r = 0; r < DD; ++r) Ash[k][r][i] = xc[r];
    __syncthreads();

    // row i of A + b_i
    float rowA[DD];
    float bb = 0.f;
#pragma unroll
    for (int j = 0; j < DD; ++j) {
        float aij = Ash[k][i][j];
        rowA[j] = aij;
        bb = fmaf(aij, means[k * DD + j], bb);
    }

    // emit A-fragments: pair P=k>>1, my row m=(k&1)*16+i; lanes m (h=0,k=0..7)
    // and m+32 (h=1,k=8..15). Split: hi=trunc16(a), lo=trunc16(a-hi).
    const int P = k >> 1;
    const int m = (k & 1) * 16 + i;
#pragma unroll
    for (int h = 0; h < 2; ++h) {
        unsigned dh[4], dl[4];
#pragma unroll
        for (int jj = 0; jj < 4; ++jj) {
            float e = rowA[h * 8 + 2 * jj];
            float o = rowA[h * 8 + 2 * jj + 1];
            unsigned he = asu(e) & 0xFFFF0000u, ho = asu(o) & 0xFFFF0000u;
            float re = e - __uint_as_float(he);
            float ro = o - __uint_as_float(ho);
            dh[jj] = (he >> 16) | ho;
            dl[jj] = ((asu(re) & 0xFFFF0000u) >> 16) | (asu(ro) & 0xFFFF0000u);
        }
        AH2[P * 64 + h * 32 + m] = make_uint4(dh[0], dh[1], dh[2], dh[3]);
        AL2[P * 64 + h * 32 + m] = make_uint4(dl[0], dl[1], dl[2], dl[3]);
    }

    // emit -b into C-layout acc-init slot: m -> (h = (m>>2)&1, t)
    {
        const int h = (m >> 2) & 1;
        const int t = (m & 3) | ((m >> 3) << 2);
        BF[P * 32 + h * 16 + t] = -bb;
    }

    if (i == 0) {
        float mx = logits[0];
        for (int t = 1; t < KC; ++t) mx = fmaxf(mx, logits[t]);
        float se = 0.f;
        for (int t = 0; t < KC; ++t) se += expf(logits[t] - mx);
        float lse = mx + logf(se);
        const float log2pi = 1.8378770664093453f;
        Cout[k] = (logits[k] - lse) - hld - 0.5f * DD * log2pi;
    }
}

// ---------------------------------------------------------------------------
// Kernel 2: 32x32x16 MFMA edition, zero LDS. Wave = 64 points = 2 sets of 32.
// Lane l loads point s*32+(l&31), dims (l>>5)*8..+7 -> already B-fragment
// layout (no transpose). Split bf16 hi/lo via mask/sub/v_perm. Per comp-pair
// P: acc init = -b (C-layout from prep), 3 split MFMAs, per-lane partial
// square-sums, ONE shfl_xor(32) per comp, online LSE on own set only.
// ---------------------------------------------------------------------------
__global__ __launch_bounds__(BLK, 4) void gmm_lp(
    const float* __restrict__ data,
    const uint4* __restrict__ AH2,
    const uint4* __restrict__ AL2,
    const float* __restrict__ BF,
    const float* __restrict__ Cg,
    float* __restrict__ out, int N)
{
    const int tid  = threadIdx.x;
    const int lane = tid & 63;
    const int half = lane >> 5;          // k-half / set ownership
    const int wbase = blockIdx.x * BLK + (tid & ~63);  // wave's first point

    // load + split both sets' B-fragments
    short8 bh[2], bl[2];
#pragma unroll
    for (int s = 0; s < 2; ++s) {
        int p = wbase + s * 32 + (lane & 31);
        p = p < N ? p : N - 1;
        const float4* xp = (const float4*)(data + (size_t)p * DD + half * 8);
        float4 v0 = xp[0], v1 = xp[1];
        float xs[8] = {v0.x, v0.y, v0.z, v0.w, v1.x, v1.y, v1.z, v1.w};
        unsigned dh[4], dl[4];
#pragma unroll
        for (int jj = 0; jj < 4; ++jj) {
            float e = xs[2 * jj], o = xs[2 * jj + 1];
            unsigned he = asu(e) & 0xFFFF0000u, ho = asu(o) & 0xFFFF0000u;
            float re = e - __uint_as_float(he);
            float ro = o - __uint_as_float(ho);
            dh[jj] = __builtin_amdgcn_perm(ho, he, 0x07060302u);
            dl[jj] = __builtin_amdgcn_perm(asu(ro), asu(re), 0x07060302u);
        }
        bh[s] = __builtin_bit_cast(short8, make_uint4(dh[0], dh[1], dh[2], dh[3]));
        bl[s] = __builtin_bit_cast(short8, make_uint4(dl[0], dl[1], dl[2], dl[3]));
    }

    float mx = -1e30f, sum = 0.f;

#pragma unroll 1
    for (int P = 0; P < 4; ++P) {
        short8 ah = __builtin_bit_cast(short8, AH2[P * 64 + lane]);
        short8 al = __builtin_bit_cast(short8, AL2[P * 64 + lane]);
        const float4* bfp = (const float4*)(BF + P * 32 + half * 16);
        float4 b0 = bfp[0], b1 = bfp[1], b2 = bfp[2], b3 = bfp[3];
        float ck0 = Cg[2 * P], ck1 = Cg[2 * P + 1];

        float me[2], mo[2];
#pragma unroll
        for (int s = 0; s < 2; ++s) {
            floatx16 acc = {b0.x, b0.y, b0.z, b0.w, b1.x, b1.y, b1.z, b1.w,
                            b2.x, b2.y, b2.z, b2.w, b3.x, b3.y, b3.z, b3.w};
            acc = __builtin_amdgcn_mfma_f32_32x32x16_bf16(ah, bh[s], acc, 0, 0, 0);
            acc = __builtin_amdgcn_mfma_f32_32x32x16_bf16(ah, bl[s], acc, 0, 0, 0);
            acc = __builtin_amdgcn_mfma_f32_32x32x16_bf16(al, bh[s], acc, 0, 0, 0);
            float se = acc[0] * acc[0], so = acc[8] * acc[8];
#pragma unroll
            for (int t = 1; t < 8; ++t) {
                se = fmaf(acc[t], acc[t], se);
                so = fmaf(acc[t + 8], acc[t + 8], so);
            }
            me[s] = se + __shfl_xor(se, 32, 64);   // full maha, comp 2P
            mo[s] = so + __shfl_xor(so, 32, 64);   // full maha, comp 2P+1
        }

        // own set only (lane l owns point wbase+l, i.e. set = half)
        float mE = half ? me[1] : me[0];
        float mO = half ? mo[1] : mo[0];

        float lpk = fmaf(-0.5f, mE, ck0);
        float nm = fmaxf(mx, lpk);
        sum = sum * __expf(mx - nm) + __expf(lpk - nm);
        mx = nm;

        lpk = fmaf(-0.5f, mO, ck1);
        nm = fmaxf(mx, lpk);
        sum = sum * __expf(mx - nm) + __expf(lpk - nm);
        mx = nm;
    }

    const int id = wbase + lane;
    if (id < N) out[id] = mx + __logf(sum);
}

extern "C" void kernel_launch(void* const* d_in, const int* in_sizes, int n_in,
                              void* d_out, int out_size, void* d_ws, size_t ws_size,
                              hipStream_t stream) {
    const float* data   = (const float*)d_in[0];
    const float* logits = (const float*)d_in[1];
    const float* means  = (const float*)d_in[2];
    const float* scales = (const float*)d_in[3];
    float* out = (float*)d_out;
    const int N = in_sizes[0] / DD;

    uint4* AH2 = (uint4*)d_ws;             // 4*64 uint4 = 4 KB
    uint4* AL2 = AH2 + 4 * 64;             // 4 KB
    float* BF  = (float*)(AL2 + 4 * 64);   // 128 floats
    float* C   = BF + 128;                 // 8 floats

    gmm_prep<<<1, 128, 0, stream>>>(logits, means, scales, AH2, AL2, BF, C);
    const int nblk = (N + BLK - 1) / BLK;
    gmm_lp<<<nblk, BLK, 0, stream>>>(data, AH2, AL2, BF, C, out, N);
}